// Round 1
// baseline (2747.773 us; speedup 1.0000x reference)
//
#include <hip/hip_runtime.h>
#include <stdint.h>

#define NBATCH 128
#define NT     64
#define OBD    32
#define ACD    8
#define LDIM   128
#define HDIM   256

typedef _Float16 h2 __attribute__((ext_vector_type(2)));
typedef float    f4 __attribute__((ext_vector_type(4)));

#if defined(__has_builtin)
#  if __has_builtin(__builtin_amdgcn_fdot2)
#    define HAVE_FDOT2 1
#  endif
#endif

__device__ __forceinline__ float dot2f(h2 a, h2 b, float c) {
#ifdef HAVE_FDOT2
  return __builtin_amdgcn_fdot2(a, b, c, false);
#else
  return c + (float)a[0] * (float)b[0] + (float)a[1] * (float)b[1];
#endif
}

__device__ __forceinline__ h2 pkh(float a, float b) {
  h2 r; r[0] = (_Float16)a; r[1] = (_Float16)b; return r;
}

__device__ __forceinline__ h2 bch(float x) { return __builtin_bit_cast(h2, x); }

__device__ __forceinline__ float sigmf(float x) { return 1.0f / (1.0f + expf(-x)); }

#define DOT4(W, I, Q) \
    a0 = dot2f(W[4*(I)+0], bch(Q.x), a0); \
    a1 = dot2f(W[4*(I)+1], bch(Q.y), a1); \
    a2 = dot2f(W[4*(I)+2], bch(Q.z), a2); \
    a3 = dot2f(W[4*(I)+3], bch(Q.w), a3);

__global__ __launch_bounds__(512)
void ode_rnn_kernel(const float* __restrict__ ob,   const float* __restrict__ acs,
                    const float* __restrict__ times,
                    const float* __restrict__ We0,  const float* __restrict__ be0,
                    const float* __restrict__ We1,  const float* __restrict__ be1,
                    const float* __restrict__ Wd0,  const float* __restrict__ bd0,
                    const float* __restrict__ Wd1,  const float* __restrict__ bd1,
                    const float* __restrict__ Wd2,  const float* __restrict__ bd2,
                    const float* __restrict__ Wo0,  const float* __restrict__ bo0,
                    const float* __restrict__ Wo1,  const float* __restrict__ bo1,
                    const float* __restrict__ Wih,  const float* __restrict__ Whh,
                    const float* __restrict__ bih,  const float* __restrict__ bn,
                    float* __restrict__ out)
{
  const int t    = threadIdx.x;
  const int b    = blockIdx.x;
  const int o2   = t & (HDIM - 1);   // 0..255  (H-sized stage output row)
  const int half = t >> 8;           // 0,1     (K-split for H-sized stages)
  const int r    = t & (LDIM - 1);   // 0..127  (L-sized stage output row)
  const int quad = t >> 7;           // 0..3    (K-split for L-sized stages)

  __shared__ __align__(16) float s_lat[LDIM];
  __shared__ __align__(16) float s_k[6][LDIM];
  __shared__ __align__(16) float s_red[HDIM];
  __shared__ __align__(16) float s_r3[3 * LDIM];
  __shared__ __align__(16) float s_dred[512];
  __shared__ __align__(16) float s_tmp[HDIM];
  __shared__ __align__(16) float s_gz[LDIM];
  __shared__ __align__(16) float s_gin[LDIM];
  __shared__ __align__(16) float s_ghn[LDIM];
  __shared__ __align__(16) float s_obs[OBD];
  __shared__ __align__(16) float s_ac[ACD];
  __shared__ __align__(16) h2    s_in16[LDIM / 2];
  __shared__ __align__(16) h2    s_a16[HDIM / 2];
  __shared__ __align__(16) h2    s_b16[HDIM / 2];

  // ---- per-thread f16 weight fragments (one-time load, stay in VGPRs) ----
  h2 w0[32], w1[64], w2[32], q0[32], q1[8];
  {
    const float2* p = (const float2*)(Wd0 + o2 * LDIM + half * 64);
#pragma unroll
    for (int i = 0; i < 32; ++i) { float2 v = p[i]; w0[i] = pkh(v.x, v.y); }
  }
  {
    const float2* p = (const float2*)(Wd1 + o2 * HDIM + half * 128);
#pragma unroll
    for (int i = 0; i < 64; ++i) { float2 v = p[i]; w1[i] = pkh(v.x, v.y); }
  }
  {
    const float2* p = (const float2*)(Wd2 + r * HDIM + quad * 64);
#pragma unroll
    for (int i = 0; i < 32; ++i) { float2 v = p[i]; w2[i] = pkh(v.x, v.y); }
  }
  {
    const float2* p = (const float2*)(Wo0 + o2 * LDIM + half * 64);
#pragma unroll
    for (int i = 0; i < 32; ++i) { float2 v = p[i]; q0[i] = pkh(v.x, v.y); }
  }
  {
    const float2* p = (const float2*)(Wo1 + (t & 31) * HDIM + (t >> 5) * 16);
#pragma unroll
    for (int i = 0; i < 8; ++i) { float2 v = p[i]; q1[i] = pkh(v.x, v.y); }
  }

  const float bb0  = bd0[o2];
  const float bb1  = bd1[o2];
  const float bb2  = bd2[r];
  const float rb0  = bo0[o2];
  const float rb1  = (t < OBD) ? bo1[t] : 0.0f;
  const float gbA  = (t < 3 * LDIM) ? bih[t] : 0.0f;
  const float bnr  = (t < LDIM) ? bn[t] : 0.0f;
  const float be1r = (t < LDIM) ? be1[t] : 0.0f;

  // ---- one dynamics-MLP eval: reads packed input s_in16, writes s_k[s][.] ----
  auto feval = [&](int s) {
    float a0, a1, a2, a3;
    // stage 1: h1 = relu(Wd0 @ z + bd0), split-K by half
    a0 = a1 = a2 = a3 = 0.0f;
    {
      const f4* src = ((const f4*)s_in16) + half * 8;
#pragma unroll
      for (int i = 0; i < 8; ++i) { f4 q = src[i]; DOT4(w0, i, q) }
    }
    if (half) s_red[o2] = a0 + a1 + a2 + a3;
    __syncthreads();
    if (!half) {
      float v = fmaxf(a0 + a1 + a2 + a3 + s_red[o2] + bb0, 0.0f);
      float ov = __shfl_xor(v, 1);
      if (!(t & 1)) s_a16[o2 >> 1] = pkh(v, ov);
    }
    __syncthreads();
    // stage 2: h2 = relu(Wd1 @ h1 + bd1)
    a0 = a1 = a2 = a3 = 0.0f;
    {
      const f4* src = ((const f4*)s_a16) + half * 16;
#pragma unroll
      for (int i = 0; i < 16; ++i) { f4 q = src[i]; DOT4(w1, i, q) }
    }
    if (half) s_red[o2] = a0 + a1 + a2 + a3;
    __syncthreads();
    if (!half) {
      float v = fmaxf(a0 + a1 + a2 + a3 + s_red[o2] + bb1, 0.0f);
      float ov = __shfl_xor(v, 1);
      if (!(t & 1)) s_b16[o2 >> 1] = pkh(v, ov);
    }
    __syncthreads();
    // stage 3: k = Wd2 @ h2 + bd2, split-K by quad
    a0 = a1 = a2 = a3 = 0.0f;
    {
      const f4* src = ((const f4*)s_b16) + quad * 8;
#pragma unroll
      for (int i = 0; i < 8; ++i) { f4 q = src[i]; DOT4(w2, i, q) }
    }
    float p = a0 + a1 + a2 + a3;
    if (quad) s_r3[(quad - 1) * LDIM + r] = p;
    __syncthreads();
    if (!quad) s_k[s][r] = p + s_r3[r] + s_r3[LDIM + r] + s_r3[2 * LDIM + r] + bb2;
  };

  // ---- one Dopri5 substep on s_lat with per-sample step hs ----
  auto substep = [&](float hs) {
#pragma unroll 1
    for (int s = 0; s < 6; ++s) {
      if (t < LDIM) {
        float z = s_lat[t];
        if      (s == 1) z += hs * (0.2f * s_k[0][t]);
        else if (s == 2) z += hs * ((3.0f/40.0f)*s_k[0][t] + (9.0f/40.0f)*s_k[1][t]);
        else if (s == 3) z += hs * ((44.0f/45.0f)*s_k[0][t] - (56.0f/15.0f)*s_k[1][t]
                                  + (32.0f/9.0f)*s_k[2][t]);
        else if (s == 4) z += hs * ((19372.0f/6561.0f)*s_k[0][t] - (25360.0f/2187.0f)*s_k[1][t]
                                  + (64448.0f/6561.0f)*s_k[2][t] - (212.0f/729.0f)*s_k[3][t]);
        else if (s == 5) z += hs * ((9017.0f/3168.0f)*s_k[0][t] - (355.0f/33.0f)*s_k[1][t]
                                  + (46732.0f/5247.0f)*s_k[2][t] + (49.0f/176.0f)*s_k[3][t]
                                  - (5103.0f/18656.0f)*s_k[4][t]);
        float ov = __shfl_xor(z, 1);
        if (!(t & 1)) s_in16[t >> 1] = pkh(z, ov);
      }
      __syncthreads();
      feval(s);
    }
    if (t < LDIM) {
      float y = s_lat[t];
      y += hs * ((35.0f/384.0f)*s_k[0][t] + (500.0f/1113.0f)*s_k[2][t]
               + (125.0f/192.0f)*s_k[3][t] - (2187.0f/6784.0f)*s_k[4][t]
               + (11.0f/84.0f)*s_k[5][t]);
      s_lat[t] = y;
    }
  };

  // ---- GRU cell (full fp32; Whh/Wih streamed from L2, 64 uses total) ----
  auto gru = [&](int ts) {
    if (t < ACD) s_ac[t] = acs[((size_t)b * NT + ts) * ACD + t];
    __syncthreads();
    float ig = gbA, hg = 0.0f;
    if (t < 3 * LDIM) {
      const float* wi = Wih + t * ACD;
#pragma unroll
      for (int j = 0; j < ACD; ++j) ig += wi[j] * s_ac[j];
      const f4* wh = (const f4*)(Whh + t * LDIM);
      const f4* xl = (const f4*)s_lat;
#pragma unroll
      for (int k2 = 0; k2 < LDIM / 4; ++k2) {
        f4 w = wh[k2], x = xl[k2];
        hg += w.x*x.x + w.y*x.y + w.z*x.z + w.w*x.w;
      }
    }
    if (t >= LDIM && t < 2 * LDIM)       s_gz[t - LDIM] = ig + hg;
    else if (t >= 2 * LDIM && t < 3 * LDIM) { s_gin[t - 2*LDIM] = ig; s_ghn[t - 2*LDIM] = hg; }
    __syncthreads();
    if (t < LDIM) {
      float rg = sigmf(ig + hg);
      float zg = sigmf(s_gz[t]);
      float ng = tanhf(s_gin[t] + rg * (s_ghn[t] + bnr));
      s_lat[t] = (1.0f - zg) * ng + zg * s_lat[t];
    }
    __syncthreads();
  };

  // ---- decoder: out[b, ts, :] = Wo1 @ relu(Wo0 @ lat + bo0) + bo1 ----
  auto decode = [&](int ts) {
    if (t < LDIM / 2) s_in16[t] = pkh(s_lat[2 * t], s_lat[2 * t + 1]);
    __syncthreads();
    float a0 = 0, a1 = 0, a2 = 0, a3 = 0;
    {
      const f4* src = ((const f4*)s_in16) + half * 8;
#pragma unroll
      for (int i = 0; i < 8; ++i) { f4 q = src[i]; DOT4(q0, i, q) }
    }
    if (half) s_red[o2] = a0 + a1 + a2 + a3;
    __syncthreads();
    if (!half) {
      float v = fmaxf(a0 + a1 + a2 + a3 + s_red[o2] + rb0, 0.0f);
      float ov = __shfl_xor(v, 1);
      if (!(t & 1)) s_a16[o2 >> 1] = pkh(v, ov);
    }
    __syncthreads();
    {
      const int sl = t >> 5;                       // 16 K-slices of 16 elems
      const f4* src = ((const f4*)s_a16) + sl * 2;
      float b0 = 0, b1 = 0;
#pragma unroll
      for (int i = 0; i < 2; ++i) {
        f4 q = src[i];
        b0 = dot2f(q1[4*i+0], bch(q.x), b0);
        b1 = dot2f(q1[4*i+1], bch(q.y), b1);
        b0 = dot2f(q1[4*i+2], bch(q.z), b0);
        b1 = dot2f(q1[4*i+3], bch(q.w), b1);
      }
      s_dred[t] = b0 + b1;
    }
    __syncthreads();
    if (t < OBD) {
      float s = rb1;
#pragma unroll
      for (int j = 0; j < 16; ++j) s += s_dred[j * OBD + t];
      out[((size_t)b * NT + ts) * OBD + t] = s;
    }
    __syncthreads();
  };

  // ================= encoder (once) =================
  if (t < OBD) s_obs[t] = ob[b * OBD + t];
  __syncthreads();
  if (t < HDIM) {
    float acc = be0[t];
    const float* wr = We0 + t * OBD;
#pragma unroll
    for (int j = 0; j < OBD; ++j) acc += wr[j] * s_obs[j];
    s_tmp[t] = fmaxf(acc, 0.0f);
  }
  __syncthreads();
  {
    float acc = 0.0f;
    const f4* wr = (const f4*)(We1 + r * HDIM + quad * 64);
    const f4* xs = (const f4*)(s_tmp + quad * 64);
#pragma unroll
    for (int k = 0; k < 16; ++k) {
      f4 w = wr[k], x = xs[k];
      acc += w.x*x.x + w.y*x.y + w.z*x.z + w.w*x.w;
    }
    if (quad) s_r3[(quad - 1) * LDIM + r] = acc;
    __syncthreads();
    if (!quad) s_lat[r] = acc + s_r3[r] + s_r3[LDIM + r] + s_r3[2 * LDIM + r] + be1r;
    __syncthreads();
  }

  // ================= time loop =================
  gru(0);
  decode(0);

#pragma unroll 1
  for (int ts = 1; ts < NT; ++ts) {
    float dt = times[b * NT + ts] - times[b * NT + ts - 1];
    float hs = 0.25f * dt;
#pragma unroll 1
    for (int sub = 0; sub < 4; ++sub) substep(hs);
    gru(ts);
    decode(ts);
  }
}

extern "C" void kernel_launch(void* const* d_in, const int* in_sizes, int n_in,
                              void* d_out, int out_size, void* d_ws, size_t ws_size,
                              hipStream_t stream) {
  (void)in_sizes; (void)n_in; (void)d_ws; (void)ws_size; (void)out_size;
  const float* ob    = (const float*)d_in[0];
  const float* acs   = (const float*)d_in[1];
  const float* times = (const float*)d_in[2];
  const float* We0   = (const float*)d_in[3];
  const float* be0   = (const float*)d_in[4];
  const float* We1   = (const float*)d_in[5];
  const float* be1   = (const float*)d_in[6];
  const float* Wd0   = (const float*)d_in[7];
  const float* bd0   = (const float*)d_in[8];
  const float* Wd1   = (const float*)d_in[9];
  const float* bd1   = (const float*)d_in[10];
  const float* Wd2   = (const float*)d_in[11];
  const float* bd2   = (const float*)d_in[12];
  const float* Wo0   = (const float*)d_in[13];
  const float* bo0   = (const float*)d_in[14];
  const float* Wo1   = (const float*)d_in[15];
  const float* bo1   = (const float*)d_in[16];
  const float* Wih   = (const float*)d_in[17];
  const float* Whh   = (const float*)d_in[18];
  const float* bih   = (const float*)d_in[19];
  const float* bn    = (const float*)d_in[20];

  ode_rnn_kernel<<<dim3(NBATCH), dim3(512), 0, stream>>>(
      ob, acs, times, We0, be0, We1, be1, Wd0, bd0, Wd1, bd1, Wd2, bd2,
      Wo0, bo0, Wo1, bo1, Wih, Whh, bih, bn, (float*)d_out);
}

// Round 2
// 2604.715 us; speedup vs baseline: 1.0549x; 1.0549x over previous
//
#include <hip/hip_runtime.h>
#include <stdint.h>

#define NBATCH 128
#define NT     64
#define OBD    32
#define ACD    8
#define LDIM   128
#define HDIM   256

typedef _Float16 h2 __attribute__((ext_vector_type(2)));
typedef float    f4 __attribute__((ext_vector_type(4)));

#if defined(__has_builtin)
#  if __has_builtin(__builtin_amdgcn_fdot2)
#    define HAVE_FDOT2 1
#  endif
#endif

__device__ __forceinline__ float dot2f(h2 a, h2 b, float c) {
#ifdef HAVE_FDOT2
  return __builtin_amdgcn_fdot2(a, b, c, false);
#else
  return c + (float)a[0] * (float)b[0] + (float)a[1] * (float)b[1];
#endif
}

__device__ __forceinline__ h2 pkh(float a, float b) {
  h2 r; r[0] = (_Float16)a; r[1] = (_Float16)b; return r;
}

__device__ __forceinline__ h2 bch(float x) { return __builtin_bit_cast(h2, x); }

__device__ __forceinline__ float sigmf(float x) { return 1.0f / (1.0f + expf(-x)); }

#define DOT4(W, I, Q) \
    a0 = dot2f(W[4*(I)+0], bch(Q.x), a0); \
    a1 = dot2f(W[4*(I)+1], bch(Q.y), a1); \
    a2 = dot2f(W[4*(I)+2], bch(Q.z), a2); \
    a3 = dot2f(W[4*(I)+3], bch(Q.w), a3);

// Split-K layout: H-sized stages use lane pairs (row p = t>>1, K-half sub = t&1),
// L-sized stages use lane quads (row r3 = t>>2, K-quarter ksub = t&3).
// All reductions via __shfl_xor (DPP) — no LDS round-trips, 4 barriers/feval.
__global__ __launch_bounds__(512, 2)
void ode_rnn_kernel(const float* __restrict__ ob,   const float* __restrict__ acs,
                    const float* __restrict__ times,
                    const float* __restrict__ We0,  const float* __restrict__ be0,
                    const float* __restrict__ We1,  const float* __restrict__ be1,
                    const float* __restrict__ Wd0,  const float* __restrict__ bd0,
                    const float* __restrict__ Wd1,  const float* __restrict__ bd1,
                    const float* __restrict__ Wd2,  const float* __restrict__ bd2,
                    const float* __restrict__ Wo0,  const float* __restrict__ bo0,
                    const float* __restrict__ Wo1,  const float* __restrict__ bo1,
                    const float* __restrict__ Wih,  const float* __restrict__ Whh,
                    const float* __restrict__ bih,  const float* __restrict__ bn,
                    float* __restrict__ out)
{
  const int t    = threadIdx.x;
  const int b    = blockIdx.x;
  const int p    = t >> 1;           // 0..255  H-stage output row
  const int sub  = t & 1;            // K-half
  const int r3   = t >> 2;           // 0..127  L-stage output row
  const int ksub = t & 3;            // K-quarter

  __shared__ __align__(16) float s_lat[LDIM];
  __shared__ __align__(16) float s_k[6][LDIM];
  __shared__ __align__(16) float s_gz[LDIM];
  __shared__ __align__(16) float s_gin[LDIM];
  __shared__ __align__(16) float s_ghn[LDIM];
  __shared__ __align__(16) float s_tmp[HDIM];
  __shared__ __align__(16) float s_obs[OBD];
  __shared__ __align__(16) float s_times[NT];
  __shared__ __align__(16) float s_acs[NT * ACD];
  __shared__ __align__(16) h2    s_in16[LDIM / 2];
  __shared__ __align__(16) h2    s_a16[HDIM / 2];
  __shared__ __align__(16) h2    s_b16[HDIM / 2];

  // ---- per-thread f16 weight fragments (one-time load, live in VGPRs) ----
  h2 w0[32], w1[64], w2[32], q0[32], q1[8];
  {
    const float2* pp = (const float2*)(Wd0 + p * LDIM + sub * 64);
#pragma unroll
    for (int i = 0; i < 32; ++i) { float2 v = pp[i]; w0[i] = pkh(v.x, v.y); }
  }
  {
    const float2* pp = (const float2*)(Wd1 + p * HDIM + sub * 128);
#pragma unroll
    for (int i = 0; i < 64; ++i) { float2 v = pp[i]; w1[i] = pkh(v.x, v.y); }
  }
  {
    const float2* pp = (const float2*)(Wd2 + r3 * HDIM + ksub * 64);
#pragma unroll
    for (int i = 0; i < 32; ++i) { float2 v = pp[i]; w2[i] = pkh(v.x, v.y); }
  }
  {
    const float2* pp = (const float2*)(Wo0 + p * LDIM + sub * 64);
#pragma unroll
    for (int i = 0; i < 32; ++i) { float2 v = pp[i]; q0[i] = pkh(v.x, v.y); }
  }
  {
    const float2* pp = (const float2*)(Wo1 + (t >> 4) * HDIM + (t & 15) * 16);
#pragma unroll
    for (int i = 0; i < 8; ++i) { float2 v = pp[i]; q1[i] = pkh(v.x, v.y); }
  }
  float wi[8];
  if (t < 3 * LDIM) {
#pragma unroll
    for (int j = 0; j < ACD; ++j) wi[j] = Wih[t * ACD + j];
  } else {
#pragma unroll
    for (int j = 0; j < ACD; ++j) wi[j] = 0.0f;
  }

  const float bb0 = bd0[p];
  const float bb1 = bd1[p];
  const float bb2 = bd2[r3];
  const float rb0 = bo0[p];
  const float rb1 = bo1[t >> 4];
  const float gbA = (t < 3 * LDIM) ? bih[t] : 0.0f;
  const float bnr = (t < LDIM) ? bn[t] : 0.0f;

  // ---- one dynamics-MLP eval: reads packed s_in16, writes s_k[s][.] ----
  auto feval = [&](int s) {
    float a0, a1, a2, a3, v;
    // stage 1: h1 = relu(Wd0 @ z + bd0)
    a0 = a1 = a2 = a3 = 0.0f;
    {
      const f4* src = ((const f4*)s_in16) + sub * 8;
#pragma unroll
      for (int i = 0; i < 8; ++i) { f4 q = src[i]; DOT4(w0, i, q) }
    }
    v = a0 + a1 + a2 + a3;
    v += __shfl_xor(v, 1);
    v = fmaxf(v + bb0, 0.0f);
    {
      float ov = __shfl_xor(v, 2);   // row 2q+1's value into lane 4q
      if ((t & 3) == 0) s_a16[t >> 2] = pkh(v, ov);
    }
    __syncthreads();
    // stage 2: h2 = relu(Wd1 @ h1 + bd1)
    a0 = a1 = a2 = a3 = 0.0f;
    {
      const f4* src = ((const f4*)s_a16) + sub * 16;
#pragma unroll
      for (int i = 0; i < 16; ++i) { f4 q = src[i]; DOT4(w1, i, q) }
    }
    v = a0 + a1 + a2 + a3;
    v += __shfl_xor(v, 1);
    v = fmaxf(v + bb1, 0.0f);
    {
      float ov = __shfl_xor(v, 2);
      if ((t & 3) == 0) s_b16[t >> 2] = pkh(v, ov);
    }
    __syncthreads();
    // stage 3: k = Wd2 @ h2 + bd2
    a0 = a1 = a2 = a3 = 0.0f;
    {
      const f4* src = ((const f4*)s_b16) + ksub * 8;
#pragma unroll
      for (int i = 0; i < 8; ++i) { f4 q = src[i]; DOT4(w2, i, q) }
    }
    v = a0 + a1 + a2 + a3;
    v += __shfl_xor(v, 1);
    v += __shfl_xor(v, 2);
    if ((t & 3) == 0) s_k[s][r3] = v + bb2;
    __syncthreads();
  };

  // ---- one Dopri5 substep on s_lat; entry assumes s_in16 holds packed lat ----
  auto substep = [&](float hs) {
#pragma unroll 1
    for (int s = 0; s < 6; ++s) {
      if (s && t < LDIM) {
        float z = s_lat[t];
        if      (s == 1) z += hs * (0.2f * s_k[0][t]);
        else if (s == 2) z += hs * ((3.0f/40.0f)*s_k[0][t] + (9.0f/40.0f)*s_k[1][t]);
        else if (s == 3) z += hs * ((44.0f/45.0f)*s_k[0][t] - (56.0f/15.0f)*s_k[1][t]
                                  + (32.0f/9.0f)*s_k[2][t]);
        else if (s == 4) z += hs * ((19372.0f/6561.0f)*s_k[0][t] - (25360.0f/2187.0f)*s_k[1][t]
                                  + (64448.0f/6561.0f)*s_k[2][t] - (212.0f/729.0f)*s_k[3][t]);
        else             z += hs * ((9017.0f/3168.0f)*s_k[0][t] - (355.0f/33.0f)*s_k[1][t]
                                  + (46732.0f/5247.0f)*s_k[2][t] + (49.0f/176.0f)*s_k[3][t]
                                  - (5103.0f/18656.0f)*s_k[4][t]);
        float ov = __shfl_xor(z, 1);
        if (!(t & 1)) s_in16[t >> 1] = pkh(z, ov);
      }
      __syncthreads();
      feval(s);
    }
    if (t < LDIM) {
      float y = s_lat[t];
      y += hs * ((35.0f/384.0f)*s_k[0][t] + (500.0f/1113.0f)*s_k[2][t]
               + (125.0f/192.0f)*s_k[3][t] - (2187.0f/6784.0f)*s_k[4][t]
               + (11.0f/84.0f)*s_k[5][t]);
      s_lat[t] = y;
      float ov = __shfl_xor(y, 1);
      if (!(t & 1)) s_in16[t >> 1] = pkh(y, ov);   // ready for next substep
    }
  };

  // ---- GRU (fp32; Whh streamed from L2); finalizes s_lat + packed s_in16 ----
  auto gru = [&](int ts) {
    __syncthreads();                 // publish s_lat
    float ig = gbA, hg = 0.0f;
    if (t < 3 * LDIM) {
      const float* xa = s_acs + ts * ACD;
#pragma unroll
      for (int j = 0; j < ACD; ++j) ig += wi[j] * xa[j];
      const f4* wh = (const f4*)(Whh + t * LDIM);
      const f4* xl = (const f4*)s_lat;
#pragma unroll
      for (int k2 = 0; k2 < LDIM / 4; ++k2) {
        f4 w = wh[k2], x = xl[k2];
        hg += w.x*x.x + w.y*x.y + w.z*x.z + w.w*x.w;
      }
    }
    if (t >= LDIM && t < 2 * LDIM)          s_gz[t - LDIM] = ig + hg;
    else if (t >= 2 * LDIM && t < 3 * LDIM) { s_gin[t - 2*LDIM] = ig; s_ghn[t - 2*LDIM] = hg; }
    __syncthreads();
    if (t < LDIM) {
      float rg = sigmf(ig + hg);
      float zg = sigmf(s_gz[t]);
      float ng = tanhf(s_gin[t] + rg * (s_ghn[t] + bnr));
      float y  = (1.0f - zg) * ng + zg * s_lat[t];
      s_lat[t] = y;
      float ov = __shfl_xor(y, 1);
      if (!(t & 1)) s_in16[t >> 1] = pkh(y, ov);
    }
  };

  // ---- decoder: out[b, ts, :] = Wo1 @ relu(Wo0 @ lat + bo0) + bo1 ----
  auto decode = [&](int ts) {
    __syncthreads();                 // publish s_in16
    float a0 = 0, a1 = 0, a2 = 0, a3 = 0, v;
    {
      const f4* src = ((const f4*)s_in16) + sub * 8;
#pragma unroll
      for (int i = 0; i < 8; ++i) { f4 q = src[i]; DOT4(q0, i, q) }
    }
    v = a0 + a1 + a2 + a3;
    v += __shfl_xor(v, 1);
    v = fmaxf(v + rb0, 0.0f);
    {
      float ov = __shfl_xor(v, 2);
      if ((t & 3) == 0) s_a16[t >> 2] = pkh(v, ov);
    }
    __syncthreads();
    // out row = t>>4 (0..31), K-slice = (t&15)*16 halfs
    a0 = a1 = a2 = a3 = 0;
    {
      const f4* src = ((const f4*)s_a16) + (t & 15) * 2;
#pragma unroll
      for (int i = 0; i < 2; ++i) {
        f4 q = src[i];
        a0 = dot2f(q1[4*i+0], bch(q.x), a0);
        a1 = dot2f(q1[4*i+1], bch(q.y), a1);
        a2 = dot2f(q1[4*i+2], bch(q.z), a2);
        a3 = dot2f(q1[4*i+3], bch(q.w), a3);
      }
    }
    v = a0 + a1 + a2 + a3;
    v += __shfl_xor(v, 1);
    v += __shfl_xor(v, 2);
    v += __shfl_xor(v, 4);
    v += __shfl_xor(v, 8);
    if ((t & 15) == 0) out[((size_t)b * NT + ts) * OBD + (t >> 4)] = v + rb1;
  };

  // ================= init + encoder =================
  if (t < OBD) s_obs[t] = ob[b * OBD + t];
  if (t < NT)  s_times[t] = times[b * NT + t];
  s_acs[t] = acs[(size_t)b * NT * ACD + t];   // NT*ACD == 512 == blockDim
  __syncthreads();
  if (t < HDIM) {
    float acc = be0[t];
    const float* wr = We0 + t * OBD;
#pragma unroll
    for (int j = 0; j < OBD; ++j) acc += wr[j] * s_obs[j];
    s_tmp[t] = fmaxf(acc, 0.0f);
  }
  __syncthreads();
  {
    const f4* wr = (const f4*)(We1 + r3 * HDIM + ksub * 64);
    const f4* xs = (const f4*)(s_tmp + ksub * 64);
    float acc = 0.0f;
#pragma unroll
    for (int k = 0; k < 16; ++k) {
      f4 w = wr[k], x = xs[k];
      acc += w.x*x.x + w.y*x.y + w.z*x.z + w.w*x.w;
    }
    acc += __shfl_xor(acc, 1);
    acc += __shfl_xor(acc, 2);
    if ((t & 3) == 0) s_lat[r3] = acc + be1[r3];
  }

  // ================= time loop =================
  gru(0);
  decode(0);

#pragma unroll 1
  for (int ts = 1; ts < NT; ++ts) {
    float hs = 0.25f * (s_times[ts] - s_times[ts - 1]);
#pragma unroll 1
    for (int su = 0; su < 4; ++su) substep(hs);
    gru(ts);
    decode(ts);
  }
}

extern "C" void kernel_launch(void* const* d_in, const int* in_sizes, int n_in,
                              void* d_out, int out_size, void* d_ws, size_t ws_size,
                              hipStream_t stream) {
  (void)in_sizes; (void)n_in; (void)d_ws; (void)ws_size; (void)out_size;
  const float* ob    = (const float*)d_in[0];
  const float* acs   = (const float*)d_in[1];
  const float* times = (const float*)d_in[2];
  const float* We0   = (const float*)d_in[3];
  const float* be0   = (const float*)d_in[4];
  const float* We1   = (const float*)d_in[5];
  const float* be1   = (const float*)d_in[6];
  const float* Wd0   = (const float*)d_in[7];
  const float* bd0   = (const float*)d_in[8];
  const float* Wd1   = (const float*)d_in[9];
  const float* bd1   = (const float*)d_in[10];
  const float* Wd2   = (const float*)d_in[11];
  const float* bd2   = (const float*)d_in[12];
  const float* Wo0   = (const float*)d_in[13];
  const float* bo0   = (const float*)d_in[14];
  const float* Wo1   = (const float*)d_in[15];
  const float* bo1   = (const float*)d_in[16];
  const float* Wih   = (const float*)d_in[17];
  const float* Whh   = (const float*)d_in[18];
  const float* bih   = (const float*)d_in[19];
  const float* bn    = (const float*)d_in[20];

  ode_rnn_kernel<<<dim3(NBATCH), dim3(512), 0, stream>>>(
      ob, acs, times, We0, be0, We1, be1, Wd0, bd0, Wd1, bd1, Wd2, bd2,
      Wo0, bo0, Wo1, bo1, Wih, Whh, bih, bn, (float*)d_out);
}

// Round 3
// 2460.978 us; speedup vs baseline: 1.1165x; 1.0584x over previous
//
#include <hip/hip_runtime.h>
#include <stdint.h>

#define NBATCH 128
#define NT     64
#define OBD    32
#define ACD    8
#define LDIM   128
#define HDIM   256

typedef _Float16 h2 __attribute__((ext_vector_type(2)));
typedef float    f4 __attribute__((ext_vector_type(4)));

#if defined(__has_builtin)
#  if __has_builtin(__builtin_amdgcn_fdot2)
#    define HAVE_FDOT2 1
#  endif
#endif

__device__ __forceinline__ float dot2f(h2 a, h2 b, float c) {
#ifdef HAVE_FDOT2
  return __builtin_amdgcn_fdot2(a, b, c, false);
#else
  return c + (float)a[0] * (float)b[0] + (float)a[1] * (float)b[1];
#endif
}

__device__ __forceinline__ h2 pkh(float a, float b) {
  h2 r; r[0] = (_Float16)a; r[1] = (_Float16)b; return r;
}

__device__ __forceinline__ h2 bch(float x) { return __builtin_bit_cast(h2, x); }

__device__ __forceinline__ float sigmf(float x) { return 1.0f / (1.0f + expf(-x)); }

#define DOT4(W, I, Q) \
    a0 = dot2f(W[4*(I)+0], bch(Q.x), a0); \
    a1 = dot2f(W[4*(I)+1], bch(Q.y), a1); \
    a2 = dot2f(W[4*(I)+2], bch(Q.z), a2); \
    a3 = dot2f(W[4*(I)+3], bch(Q.w), a3);

// H-stages: row p = t>>1, K-half sub = t&1. L-stages: row r3 = t>>2, K-quarter
// ksub = t&3. All reductions via __shfl_xor. s_b16 is padded (+2 f4 per 8-f4
// slice) so the 4 ksub slice bases hit banks {0,8,16,24} — no 4-way conflict.
// launch_bounds(512,1): allow up to 256 arch VGPRs so the 168 h2 weight regs
// do NOT spill (r2: cap 128 -> 50 MB scratch writes, VALUBusy 17%).
__global__ __launch_bounds__(512, 1)
void ode_rnn_kernel(const float* __restrict__ ob,   const float* __restrict__ acs,
                    const float* __restrict__ times,
                    const float* __restrict__ We0,  const float* __restrict__ be0,
                    const float* __restrict__ We1,  const float* __restrict__ be1,
                    const float* __restrict__ Wd0,  const float* __restrict__ bd0,
                    const float* __restrict__ Wd1,  const float* __restrict__ bd1,
                    const float* __restrict__ Wd2,  const float* __restrict__ bd2,
                    const float* __restrict__ Wo0,  const float* __restrict__ bo0,
                    const float* __restrict__ Wo1,  const float* __restrict__ bo1,
                    const float* __restrict__ Wih,  const float* __restrict__ Whh,
                    const float* __restrict__ bih,  const float* __restrict__ bn,
                    float* __restrict__ out)
{
  const int t    = threadIdx.x;
  const int b    = blockIdx.x;
  const int p    = t >> 1;           // 0..255  H-stage output row
  const int sub  = t & 1;            // K-half
  const int r3   = t >> 2;           // 0..127  L-stage output row
  const int ksub = t & 3;            // K-quarter

  __shared__ __align__(16) float s_lat[LDIM];
  __shared__ __align__(16) float s_k[5][LDIM];
  __shared__ __align__(16) float s_gz[LDIM];
  __shared__ __align__(16) float s_gin[LDIM];
  __shared__ __align__(16) float s_ghn[LDIM];
  __shared__ __align__(16) float s_tmp[HDIM];
  __shared__ __align__(16) float s_obs[OBD];
  __shared__ __align__(16) float s_times[NT];
  __shared__ __align__(16) float s_acs[NT * ACD];
  __shared__ __align__(16) h2    s_in16[LDIM / 2];
  __shared__ __align__(16) h2    s_a16[HDIM / 2];
  __shared__ __align__(16) h2    s_b16[HDIM / 2 + 24];   // +2 f4 pad per slice

  // ---- per-thread f16 weight fragments (one-time load, live in VGPRs) ----
  h2 w0[32], w1[64], w2[32], q0[32], q1[8];
  {
    const float2* pp = (const float2*)(Wd0 + p * LDIM + sub * 64);
#pragma unroll
    for (int i = 0; i < 32; ++i) { float2 v = pp[i]; w0[i] = pkh(v.x, v.y); }
  }
  {
    const float2* pp = (const float2*)(Wd1 + p * HDIM + sub * 128);
#pragma unroll
    for (int i = 0; i < 64; ++i) { float2 v = pp[i]; w1[i] = pkh(v.x, v.y); }
  }
  {
    const float2* pp = (const float2*)(Wd2 + r3 * HDIM + ksub * 64);
#pragma unroll
    for (int i = 0; i < 32; ++i) { float2 v = pp[i]; w2[i] = pkh(v.x, v.y); }
  }
  {
    const float2* pp = (const float2*)(Wo0 + p * LDIM + sub * 64);
#pragma unroll
    for (int i = 0; i < 32; ++i) { float2 v = pp[i]; q0[i] = pkh(v.x, v.y); }
  }
  {
    const float2* pp = (const float2*)(Wo1 + (t >> 4) * HDIM + (t & 15) * 16);
#pragma unroll
    for (int i = 0; i < 8; ++i) { float2 v = pp[i]; q1[i] = pkh(v.x, v.y); }
  }
  float wi[8];
  if (t < 3 * LDIM) {
#pragma unroll
    for (int j = 0; j < ACD; ++j) wi[j] = Wih[t * ACD + j];
  } else {
#pragma unroll
    for (int j = 0; j < ACD; ++j) wi[j] = 0.0f;
  }

  const float bb0 = bd0[p];
  const float bb1 = bd1[p];
  const float bb2 = bd2[r3];
  const float rb0 = bo0[p];
  const float rb1 = bo1[t >> 4];
  const float gbA = (t < 3 * LDIM) ? bih[t] : 0.0f;
  const float bnr = (t < LDIM) ? bn[t] : 0.0f;

  // ---- one Dopri5 substep; entry: s_in16 = packed lat, s_lat = lat ----
  auto substep = [&](float hs) {
#pragma unroll
    for (int s = 0; s < 6; ++s) {
      float a0, a1, a2, a3, v;
      // stage 1: h1 = relu(Wd0 @ z + bd0)
      a0 = a1 = a2 = a3 = 0.0f;
      {
        const f4* src = ((const f4*)s_in16) + sub * 8;
#pragma unroll
        for (int i = 0; i < 8; ++i) { f4 q = src[i]; DOT4(w0, i, q) }
      }
      v = a0 + a1 + a2 + a3;
      v += __shfl_xor(v, 1);
      v = fmaxf(v + bb0, 0.0f);
      { float ov = __shfl_xor(v, 2); if ((t & 3) == 0) s_a16[t >> 2] = pkh(v, ov); }
      __syncthreads();
      // stage 2: h2 = relu(Wd1 @ h1 + bd1)
      a0 = a1 = a2 = a3 = 0.0f;
      {
        const f4* src = ((const f4*)s_a16) + sub * 16;
#pragma unroll
        for (int i = 0; i < 16; ++i) { f4 q = src[i]; DOT4(w1, i, q) }
      }
      v = a0 + a1 + a2 + a3;
      v += __shfl_xor(v, 1);
      v = fmaxf(v + bb1, 0.0f);
      { float ov = __shfl_xor(v, 2);
        if ((t & 3) == 0) s_b16[(t >> 2) + ((t >> 7) << 3)] = pkh(v, ov); }
      __syncthreads();
      // stage 3: k_s = Wd2 @ h2 + bd2, fused with RK tail
      a0 = a1 = a2 = a3 = 0.0f;
      {
        const f4* src = ((const f4*)s_b16) + ksub * 10;   // padded slice stride
#pragma unroll
        for (int i = 0; i < 8; ++i) { f4 q = src[i]; DOT4(w2, i, q) }
      }
      v = a0 + a1 + a2 + a3;
      v += __shfl_xor(v, 1);
      v += __shfl_xor(v, 2);
      float kv = v + bb2;                     // k_s[r3], in every lane of quad
      if (s < 5 && (t & 3) == 0) s_k[s][r3] = kv;
      float base = s_lat[r3];
      float z;
      if (s == 0)
        z = base + hs * (0.2f * kv);
      else if (s == 1)
        z = base + hs * ((3.0f/40.0f)*s_k[0][r3] + (9.0f/40.0f)*kv);
      else if (s == 2)
        z = base + hs * ((44.0f/45.0f)*s_k[0][r3] - (56.0f/15.0f)*s_k[1][r3]
                       + (32.0f/9.0f)*kv);
      else if (s == 3)
        z = base + hs * ((19372.0f/6561.0f)*s_k[0][r3] - (25360.0f/2187.0f)*s_k[1][r3]
                       + (64448.0f/6561.0f)*s_k[2][r3] - (212.0f/729.0f)*kv);
      else if (s == 4)
        z = base + hs * ((9017.0f/3168.0f)*s_k[0][r3] - (355.0f/33.0f)*s_k[1][r3]
                       + (46732.0f/5247.0f)*s_k[2][r3] + (49.0f/176.0f)*s_k[3][r3]
                       - (5103.0f/18656.0f)*kv);
      else
        z = base + hs * ((35.0f/384.0f)*s_k[0][r3] + (500.0f/1113.0f)*s_k[2][r3]
                       + (125.0f/192.0f)*s_k[3][r3] - (2187.0f/6784.0f)*s_k[4][r3]
                       + (11.0f/84.0f)*kv);
      { float ov = __shfl_xor(z, 4); if ((t & 7) == 0) s_in16[t >> 3] = pkh(z, ov); }
      if (s == 5 && (t & 3) == 0) s_lat[r3] = z;
      __syncthreads();
    }
  };

  // ---- GRU (fp32; Whh streamed from L2); finalizes s_lat + packed s_in16 ----
  auto gru = [&](int ts) {
    __syncthreads();                 // publish s_lat
    float ig = gbA, hg = 0.0f;
    if (t < 3 * LDIM) {
      const float* xa = s_acs + ts * ACD;
#pragma unroll
      for (int j = 0; j < ACD; ++j) ig += wi[j] * xa[j];
      const f4* wh = (const f4*)(Whh + t * LDIM);
      const f4* xl = (const f4*)s_lat;
#pragma unroll
      for (int k2 = 0; k2 < LDIM / 4; ++k2) {
        f4 w = wh[k2], x = xl[k2];
        hg += w.x*x.x + w.y*x.y + w.z*x.z + w.w*x.w;
      }
    }
    if (t >= LDIM && t < 2 * LDIM)          s_gz[t - LDIM] = ig + hg;
    else if (t >= 2 * LDIM && t < 3 * LDIM) { s_gin[t - 2*LDIM] = ig; s_ghn[t - 2*LDIM] = hg; }
    __syncthreads();
    if (t < LDIM) {
      float rg = sigmf(ig + hg);
      float zg = sigmf(s_gz[t]);
      float ng = tanhf(s_gin[t] + rg * (s_ghn[t] + bnr));
      float y  = (1.0f - zg) * ng + zg * s_lat[t];
      s_lat[t] = y;
      float ov = __shfl_xor(y, 1);
      if (!(t & 1)) s_in16[t >> 1] = pkh(y, ov);
    }
  };

  // ---- decoder: out[b, ts, :] = Wo1 @ relu(Wo0 @ lat + bo0) + bo1 ----
  auto decode = [&](int ts) {
    __syncthreads();                 // publish s_in16
    float a0 = 0, a1 = 0, a2 = 0, a3 = 0, v;
    {
      const f4* src = ((const f4*)s_in16) + sub * 8;
#pragma unroll
      for (int i = 0; i < 8; ++i) { f4 q = src[i]; DOT4(q0, i, q) }
    }
    v = a0 + a1 + a2 + a3;
    v += __shfl_xor(v, 1);
    v = fmaxf(v + rb0, 0.0f);
    { float ov = __shfl_xor(v, 2); if ((t & 3) == 0) s_a16[t >> 2] = pkh(v, ov); }
    __syncthreads();
    // out row = t>>4 (0..31), K-slice = (t&15)*16 halfs
    a0 = a1 = a2 = a3 = 0;
    {
      const f4* src = ((const f4*)s_a16) + (t & 15) * 2;
#pragma unroll
      for (int i = 0; i < 2; ++i) {
        f4 q = src[i];
        a0 = dot2f(q1[4*i+0], bch(q.x), a0);
        a1 = dot2f(q1[4*i+1], bch(q.y), a1);
        a2 = dot2f(q1[4*i+2], bch(q.z), a2);
        a3 = dot2f(q1[4*i+3], bch(q.w), a3);
      }
    }
    v = a0 + a1 + a2 + a3;
    v += __shfl_xor(v, 1);
    v += __shfl_xor(v, 2);
    v += __shfl_xor(v, 4);
    v += __shfl_xor(v, 8);
    if ((t & 15) == 0) out[((size_t)b * NT + ts) * OBD + (t >> 4)] = v + rb1;
    __syncthreads();                 // protect s_a16 before next substep
  };

  // ================= init + encoder =================
  if (t < OBD) s_obs[t] = ob[b * OBD + t];
  if (t < NT)  s_times[t] = times[b * NT + t];
  s_acs[t] = acs[(size_t)b * NT * ACD + t];   // NT*ACD == 512 == blockDim
  __syncthreads();
  if (t < HDIM) {
    float acc = be0[t];
    const float* wr = We0 + t * OBD;
#pragma unroll
    for (int j = 0; j < OBD; ++j) acc += wr[j] * s_obs[j];
    s_tmp[t] = fmaxf(acc, 0.0f);
  }
  __syncthreads();
  {
    const f4* wr = (const f4*)(We1 + r3 * HDIM + ksub * 64);
    const f4* xs = (const f4*)(s_tmp + ksub * 64);
    float acc = 0.0f;
#pragma unroll
    for (int k = 0; k < 16; ++k) {
      f4 w = wr[k], x = xs[k];
      acc += w.x*x.x + w.y*x.y + w.z*x.z + w.w*x.w;
    }
    acc += __shfl_xor(acc, 1);
    acc += __shfl_xor(acc, 2);
    if ((t & 3) == 0) s_lat[r3] = acc + be1[r3];
  }

  // ================= time loop =================
  gru(0);
  decode(0);

#pragma unroll 1
  for (int ts = 1; ts < NT; ++ts) {
    float hs = 0.25f * (s_times[ts] - s_times[ts - 1]);
#pragma unroll 1
    for (int su = 0; su < 4; ++su) substep(hs);
    gru(ts);
    decode(ts);
  }
}

extern "C" void kernel_launch(void* const* d_in, const int* in_sizes, int n_in,
                              void* d_out, int out_size, void* d_ws, size_t ws_size,
                              hipStream_t stream) {
  (void)in_sizes; (void)n_in; (void)d_ws; (void)ws_size; (void)out_size;
  const float* ob    = (const float*)d_in[0];
  const float* acs   = (const float*)d_in[1];
  const float* times = (const float*)d_in[2];
  const float* We0   = (const float*)d_in[3];
  const float* be0   = (const float*)d_in[4];
  const float* We1   = (const float*)d_in[5];
  const float* be1   = (const float*)d_in[6];
  const float* Wd0   = (const float*)d_in[7];
  const float* bd0   = (const float*)d_in[8];
  const float* Wd1   = (const float*)d_in[9];
  const float* bd1   = (const float*)d_in[10];
  const float* Wd2   = (const float*)d_in[11];
  const float* bd2   = (const float*)d_in[12];
  const float* Wo0   = (const float*)d_in[13];
  const float* bo0   = (const float*)d_in[14];
  const float* Wo1   = (const float*)d_in[15];
  const float* bo1   = (const float*)d_in[16];
  const float* Wih   = (const float*)d_in[17];
  const float* Whh   = (const float*)d_in[18];
  const float* bih   = (const float*)d_in[19];
  const float* bn    = (const float*)d_in[20];

  ode_rnn_kernel<<<dim3(NBATCH), dim3(512), 0, stream>>>(
      ob, acs, times, We0, be0, We1, be1, Wd0, bd0, Wd1, bd1, Wd2, bd2,
      Wo0, bo0, Wo1, bo1, Wih, Whh, bih, bn, (float*)d_out);
}